// Round 1
// baseline (101.150 us; speedup 1.0000x reference)
//
#include <hip/hip_runtime.h>
#include <hip/hip_bf16.h>
#include <cstdint>

#define DEV_INLINE __device__ __forceinline__

constexpr int BSZ = 2, NUM_Q = 256, NUM_K = 2048, D_IN = 512, D_ATT = 128;
constexpr float S_ATT = 0.08838834764831845f;  // 1/sqrt(128), folded into qb

DEV_INLINE float fast_tanh(float x) {
  // tanh(x) = 1 - 2/(e^{2x}+1); exp->inf => 1, exp->0 => -1, branch-free
  float e = __expf(2.0f * x);
  return 1.0f - 2.0f * __builtin_amdgcn_rcpf(e + 1.0f);
}

DEV_INLINE void unpack8(const uint4& u, float* f) {
  f[0] = __uint_as_float(u.x << 16); f[1] = __uint_as_float(u.x & 0xffff0000u);
  f[2] = __uint_as_float(u.y << 16); f[3] = __uint_as_float(u.y & 0xffff0000u);
  f[4] = __uint_as_float(u.z << 16); f[5] = __uint_as_float(u.z & 0xffff0000u);
  f[6] = __uint_as_float(u.w << 16); f[7] = __uint_as_float(u.w & 0xffff0000u);
}

// X [rows,512] @ {Wl,Wb} [512,128] + bias -> outl/outb [rows,128]
// 16 rows per block, 256 threads = 2 row-groups x 128 d-lanes.
template <bool WRITE_BF16>
__global__ __launch_bounds__(256) void proj_kernel(
    const float* __restrict__ X,
    const float* __restrict__ Wl, const float* __restrict__ bl,
    const float* __restrict__ Wb, const float* __restrict__ bb,
    float scale_b, void* __restrict__ outl, void* __restrict__ outb) {
  __shared__ float xs[16 * D_IN];  // 32 KB
  const int tid = threadIdx.x;
  const long row0 = (long)blockIdx.x * 16;
  const float* Xg = X + row0 * D_IN;
#pragma unroll
  for (int i = 0; i < 8; ++i) {
    const int idx = tid + i * 256;  // 2048 float4
    ((float4*)xs)[idx] = ((const float4*)Xg)[idx];
  }
  __syncthreads();
  const int d = tid & 127;
  const int rg = tid >> 7;
  float accl[8], accb[8];
#pragma unroll
  for (int r = 0; r < 8; ++r) { accl[r] = 0.f; accb[r] = 0.f; }
  for (int j = 0; j < D_IN; j += 4) {
    float wl[4], wb[4];
#pragma unroll
    for (int jj = 0; jj < 4; ++jj) {
      wl[jj] = Wl[(j + jj) * D_ATT + d];
      wb[jj] = Wb[(j + jj) * D_ATT + d];
    }
#pragma unroll
    for (int r = 0; r < 8; ++r) {
      const float4 xv = *(const float4*)&xs[(rg * 8 + r) * D_IN + j];
      accl[r] = fmaf(xv.x, wl[0], accl[r]);
      accl[r] = fmaf(xv.y, wl[1], accl[r]);
      accl[r] = fmaf(xv.z, wl[2], accl[r]);
      accl[r] = fmaf(xv.w, wl[3], accl[r]);
      accb[r] = fmaf(xv.x, wb[0], accb[r]);
      accb[r] = fmaf(xv.y, wb[1], accb[r]);
      accb[r] = fmaf(xv.z, wb[2], accb[r]);
      accb[r] = fmaf(xv.w, wb[3], accb[r]);
    }
  }
  const float blv = bl[d], bbv = bb[d];
#pragma unroll
  for (int r = 0; r < 8; ++r) {
    const long row = row0 + rg * 8 + r;
    const float ol = accl[r] + blv;
    const float ob = (accb[r] + bbv) * scale_b;
    if (WRITE_BF16) {
      ((__hip_bfloat16*)outl)[row * D_ATT + d] = __float2bfloat16(ol);
      ((__hip_bfloat16*)outb)[row * D_ATT + d] = __float2bfloat16(ob);
    } else {
      ((float*)outl)[row * D_ATT + d] = ol;
      ((float*)outb)[row * D_ATT + d] = ob;
    }
  }
}

// Fused: out[b,q,k] = sum_d v[d]*tanh(ql+kl) + qb.kb (qb pre-scaled) + b_att
// Block: 256 thr = 64 k-lanes x 4 waves; tile 64 k x 16 q; LDS 49 KB.
__global__ __launch_bounds__(256) void fused_kernel(
    const float* __restrict__ ql_g, const float* __restrict__ qb_g,
    const uint16_t* __restrict__ kl_g, const uint16_t* __restrict__ kb_g,
    const float* __restrict__ v_att, const float* __restrict__ b_att,
    float* __restrict__ out) {
  __shared__ __align__(16) unsigned char klds[64 * 256];   // bf16, swizzled
  __shared__ __align__(16) unsigned char kblds[64 * 256];  // bf16, swizzled
  __shared__ float qlds[16 * D_ATT];
  __shared__ float qblds[16 * D_ATT];
  __shared__ float vlds[D_ATT];

  const int tid = threadIdx.x;
  const int b = blockIdx.x >> 9;
  const int qt = (blockIdx.x >> 5) & 15;
  const int kt = blockIdx.x & 31;

  // stage k-tiles: 64 rows x 256B each, XOR-swizzle 16B chunks within row
  const uint4* klg = (const uint4*)(kl_g + (long)(b * NUM_K + kt * 64) * D_ATT);
  const uint4* kbg = (const uint4*)(kb_g + (long)(b * NUM_K + kt * 64) * D_ATT);
#pragma unroll
  for (int i = 0; i < 4; ++i) {
    const int f = tid + i * 256;  // 1024 16B chunks
    const int kr = f >> 4, c = f & 15;
    const int off = kr * 256 + (((c ^ (kr & 7))) << 4);
    *(uint4*)(klds + off) = klg[f];
    *(uint4*)(kblds + off) = kbg[f];
  }
  // stage q-tiles (fp32 linear, read as wave-uniform broadcasts)
  const float4* qlg = (const float4*)(ql_g + (long)(b * NUM_Q + qt * 16) * D_ATT);
  const float4* qbg = (const float4*)(qb_g + (long)(b * NUM_Q + qt * 16) * D_ATT);
#pragma unroll
  for (int i = 0; i < 2; ++i) {
    const int idx = tid + i * 256;  // 512 float4
    ((float4*)qlds)[idx] = qlg[idx];
    ((float4*)qblds)[idx] = qbg[idx];
  }
  if (tid < 32) ((float4*)vlds)[tid] = ((const float4*)v_att)[tid];
  __syncthreads();

  const int k = tid & 63;
  const int w = tid >> 6;  // wave id -> q group (wave-uniform)
  float accl[4] = {0.f, 0.f, 0.f, 0.f};
  float accb[4] = {0.f, 0.f, 0.f, 0.f};

  for (int d0 = 0; d0 < D_ATT; d0 += 8) {
    const int c = d0 >> 3;
    const int off = k * 256 + (((c ^ (k & 7))) << 4);
    const uint4 klv = *(const uint4*)(klds + off);
    const uint4 kbv = *(const uint4*)(kblds + off);
    float klf[8], kbf[8];
    unpack8(klv, klf);
    unpack8(kbv, kbf);
    float vv[8];
    *(float4*)&vv[0] = *(const float4*)&vlds[d0];
    *(float4*)&vv[4] = *(const float4*)&vlds[d0 + 4];
#pragma unroll
    for (int qq = 0; qq < 4; ++qq) {
      const int q = w * 4 + qq;
      float qlv[8], qbv2[8];
      *(float4*)&qlv[0] = *(const float4*)&qlds[q * D_ATT + d0];
      *(float4*)&qlv[4] = *(const float4*)&qlds[q * D_ATT + d0 + 4];
      *(float4*)&qbv2[0] = *(const float4*)&qblds[q * D_ATT + d0];
      *(float4*)&qbv2[4] = *(const float4*)&qblds[q * D_ATT + d0 + 4];
#pragma unroll
      for (int j = 0; j < 8; ++j) {
        const float x = qlv[j] + klf[j];
        const float t = fast_tanh(x);
        accl[qq] = fmaf(vv[j], t, accl[qq]);
        accb[qq] = fmaf(qbv2[j], kbf[j], accb[qq]);
      }
    }
  }

  const float batt = b_att[0];
#pragma unroll
  for (int qq = 0; qq < 4; ++qq) {
    const int q = qt * 16 + w * 4 + qq;
    out[(long)(b * NUM_Q + q) * NUM_K + kt * 64 + k] = accl[qq] + accb[qq] + batt;
  }
}

extern "C" void kernel_launch(void* const* d_in, const int* in_sizes, int n_in,
                              void* d_out, int out_size, void* d_ws, size_t ws_size,
                              hipStream_t stream) {
  const float* query = (const float*)d_in[0];
  const float* key   = (const float*)d_in[1];
  const float* W_bq  = (const float*)d_in[2];
  const float* b_bq  = (const float*)d_in[3];
  const float* W_bk  = (const float*)d_in[4];
  const float* b_bk  = (const float*)d_in[5];
  const float* W_lq  = (const float*)d_in[6];
  const float* b_lq  = (const float*)d_in[7];
  const float* W_lk  = (const float*)d_in[8];
  const float* b_lk  = (const float*)d_in[9];
  const float* v_att = (const float*)d_in[10];
  const float* b_att = (const float*)d_in[11];

  // workspace: ql,qb fp32 [512,128]; kl,kb bf16 [4096,128]  (2.5 MB total)
  float* ql = (float*)d_ws;
  float* qb = ql + BSZ * NUM_Q * D_ATT;
  __hip_bfloat16* kl = (__hip_bfloat16*)(qb + BSZ * NUM_Q * D_ATT);
  __hip_bfloat16* kb = kl + BSZ * NUM_K * D_ATT;

  proj_kernel<false><<<(BSZ * NUM_Q) / 16, 256, 0, stream>>>(
      query, W_lq, b_lq, W_bq, b_bq, S_ATT, (void*)ql, (void*)qb);
  proj_kernel<true><<<(BSZ * NUM_K) / 16, 256, 0, stream>>>(
      key, W_lk, b_lk, W_bk, b_bk, 1.0f, (void*)kl, (void*)kb);
  fused_kernel<<<BSZ * 16 * 32, 256, 0, stream>>>(
      ql, qb, (const uint16_t*)kl, (const uint16_t*)kb, v_att, b_att,
      (float*)d_out);
}

// Round 3
// 68.098 us; speedup vs baseline: 1.4853x; 1.4853x over previous
//
#include <hip/hip_runtime.h>
#include <hip/hip_bf16.h>
#include <cstdint>

#define DEV_INLINE __device__ __forceinline__

typedef __attribute__((ext_vector_type(8))) short short8v;   // 8 bf16 (4 VGPRs)
typedef __attribute__((ext_vector_type(4))) float f32x4;

constexpr int BSZ = 2, NUM_Q = 256, NUM_K = 2048, D_IN = 512, D_ATT = 128;
constexpr float S_ATT = 0.08838834764831845f;   // 1/sqrt(128)
constexpr float C2 = 2.8853900817779268f;       // 2*log2(e): exp2(C2*x) = e^{2x}

DEV_INLINE uint16_t f2bf(float f) {  // fp32 -> bf16 bits, round-nearest-even
  uint32_t u = __float_as_uint(f);
  return (uint16_t)((u + 0x7fffu + ((u >> 16) & 1u)) >> 16);
}

DEV_INLINE void unpack8(const uint4& u, float* f) {
  f[0] = __uint_as_float(u.x << 16); f[1] = __uint_as_float(u.x & 0xffff0000u);
  f[2] = __uint_as_float(u.y << 16); f[3] = __uint_as_float(u.y & 0xffff0000u);
  f[4] = __uint_as_float(u.z << 16); f[5] = __uint_as_float(u.z & 0xffff0000u);
  f[6] = __uint_as_float(u.w << 16); f[7] = __uint_as_float(u.w & 0xffff0000u);
}

DEV_INLINE float fast_exp2(float x) {
#if __has_builtin(__builtin_amdgcn_exp2f)
  return __builtin_amdgcn_exp2f(x);
#else
  return __expf(0.6931471805599453f * x);
#endif
}

// ---------------------------------------------------------------------------
// pack_w: Wt2[mat][c][k] = bf16(W[k][c]); mat0={W_lq|W_bq}, mat1={W_lk|W_bk}.
// Also vsumc[0] = sum_d v_att[d] + b_att.
// ---------------------------------------------------------------------------
__global__ __launch_bounds__(256) void pack_w(
    const float* __restrict__ Wlq, const float* __restrict__ Wbq,
    const float* __restrict__ Wlk, const float* __restrict__ Wbk,
    const float* __restrict__ v_att, const float* __restrict__ b_att,
    uint16_t* __restrict__ Wt2, float* __restrict__ vsumc) {
  const int flat = blockIdx.x * 256 + threadIdx.x;  // 32768 total
  const int mat = flat >> 14;                        // 0..1
  const int rem = flat & 16383;
  const int c = rem >> 6;                            // 0..255
  const int k0 = (rem & 63) * 8;                     // 0..504
  const float* W = (mat == 0) ? (c < 128 ? Wlq : Wbq) : (c < 128 ? Wlk : Wbk);
  const int cs = c & 127;
  uint16_t o[8];
#pragma unroll
  for (int j = 0; j < 8; ++j) o[j] = f2bf(W[(k0 + j) * D_ATT + cs]);
  *(uint4*)(Wt2 + (size_t)mat * 256 * 512 + (size_t)c * 512 + k0) =
      *(const uint4*)o;

  if (blockIdx.x == 0 && threadIdx.x < 64) {
    float s = v_att[threadIdx.x] + v_att[threadIdx.x + 64];
#pragma unroll
    for (int off = 32; off >= 1; off >>= 1) s += __shfl_down(s, off);
    if (threadIdx.x == 0) vsumc[0] = s + b_att[0];
  }
}

// ---------------------------------------------------------------------------
// proj_gemm: [query;key] (4608x512) @ Wt2 -> ql,qb (fp32, pre-scaled), kl,kb
// (bf16). One wave per 16 rows x 32 cols; K-loop 16 x mfma_f32_16x16x32_bf16.
// Assumed frag maps (consistent for A and B, so any k-permutation cancels):
//   A: row = lane&15, k = (lane>>4)*8 + j;  B: col = lane&15, same k map.
//   C/D: col = lane&15, row = (lane>>4)*4 + reg   [m89-verified]
// ---------------------------------------------------------------------------
__global__ __launch_bounds__(256) void proj_gemm(
    const float* __restrict__ Xq, const float* __restrict__ Xk,
    const uint16_t* __restrict__ Wt2,
    const float* __restrict__ b_lq, const float* __restrict__ b_bq,
    const float* __restrict__ b_lk, const float* __restrict__ b_bk,
    float* __restrict__ ql, float* __restrict__ qb,
    uint16_t* __restrict__ kl, uint16_t* __restrict__ kb) {
  const int wid = blockIdx.x * 4 + (threadIdx.x >> 6);  // 0..2303
  const int l = threadIdx.x & 63;
  const int rt = wid >> 3;   // 0..287 row-tile (16 rows)
  const int ct2 = wid & 7;   // 0..7  col-group (32 cols)
  const bool isq = rt < 32;
  const float* X = isq ? Xq : Xk;
  const int row0 = isq ? rt * 16 : (rt - 32) * 16;  // local row in q/k buffer
  const int lk = (l >> 4) * 8;
  const float* xrow = X + (size_t)(row0 + (l & 15)) * D_IN + lk;
  const uint16_t* w0 =
      Wt2 + (isq ? 0 : (size_t)256 * 512) + (size_t)(ct2 * 32 + (l & 15)) * 512 + lk;
  const uint16_t* w1 = w0 + 16 * 512;

  f32x4 acc0 = {0.f, 0.f, 0.f, 0.f}, acc1 = {0.f, 0.f, 0.f, 0.f};
  for (int s = 0; s < 16; ++s) {
    const int k0 = s * 32;
    const float4 x0 = *(const float4*)(xrow + k0);
    const float4 x1 = *(const float4*)(xrow + k0 + 4);
    short8v a;
    a[0] = (short)f2bf(x0.x); a[1] = (short)f2bf(x0.y);
    a[2] = (short)f2bf(x0.z); a[3] = (short)f2bf(x0.w);
    a[4] = (short)f2bf(x1.x); a[5] = (short)f2bf(x1.y);
    a[6] = (short)f2bf(x1.z); a[7] = (short)f2bf(x1.w);
    const short8v b0 = *(const short8v*)(w0 + k0);
    const short8v b1 = *(const short8v*)(w1 + k0);
    acc0 = __builtin_amdgcn_mfma_f32_16x16x32_bf16(a, b0, acc0, 0, 0, 0);
    acc1 = __builtin_amdgcn_mfma_f32_16x16x32_bf16(a, b1, acc1, 0, 0, 0);
  }

  const int lrow4 = (l >> 4) * 4;
#pragma unroll
  for (int half = 0; half < 2; ++half) {
    const f32x4 acc = half ? acc1 : acc0;
    const int cb = ct2 * 32 + half * 16;  // wave-uniform
    const int c = cb + (l & 15);
    const int cl = c & 127;
    float bias;
    if (isq) bias = (cb < 128) ? b_lq[cl] : b_bq[cl];
    else     bias = (cb < 128) ? b_lk[cl] : b_bk[cl];
#pragma unroll
    for (int jr = 0; jr < 4; ++jr) {
      const int row = row0 + lrow4 + jr;
      const float val = acc[jr] + bias;
      if (isq) {
        if (cb < 128) ql[row * D_ATT + cl] = val * C2;
        else          qb[row * D_ATT + cl] = val * S_ATT;
      } else {
        if (cb < 128) kl[row * D_ATT + cl] = f2bf(val * C2);
        else          kb[row * D_ATT + cl] = f2bf(val);
      }
    }
  }
}

// ---------------------------------------------------------------------------
// fused: out[b,q,k] = VSUM + b_att + sum_d (-2 v_d) * sigm + qb.kb
//        where sigm = 1/(1+exp2(ql+kl))   (ql,kl pre-scaled by 2*log2e)
// Block: 256 thr = 64 k-lanes x 4 waves; tile 64 k x 16 q; LDS ~49 KB.
// ---------------------------------------------------------------------------
__global__ __launch_bounds__(256) void fused_kernel(
    const float* __restrict__ ql_g, const float* __restrict__ qb_g,
    const uint16_t* __restrict__ kl_g, const uint16_t* __restrict__ kb_g,
    const float* __restrict__ v_att, const float* __restrict__ vsumc,
    float* __restrict__ out) {
  __shared__ __align__(16) unsigned char klds[64 * 256];   // bf16, swizzled
  __shared__ __align__(16) unsigned char kblds[64 * 256];  // bf16, swizzled
  __shared__ float qlds[16 * D_ATT];
  __shared__ float qblds[16 * D_ATT];
  __shared__ float vlds[D_ATT];  // -2 * v_att

  const int tid = threadIdx.x;
  const int b = blockIdx.x >> 9;
  const int qt = (blockIdx.x >> 5) & 15;
  const int kt = blockIdx.x & 31;

  const uint4* klg = (const uint4*)(kl_g + (size_t)(b * NUM_K + kt * 64) * D_ATT);
  const uint4* kbg = (const uint4*)(kb_g + (size_t)(b * NUM_K + kt * 64) * D_ATT);
#pragma unroll
  for (int i = 0; i < 4; ++i) {
    const int f = tid + i * 256;
    const int kr = f >> 4, c = f & 15;
    const int off = kr * 256 + ((c ^ (kr & 7)) << 4);
    *(uint4*)(klds + off) = klg[f];
    *(uint4*)(kblds + off) = kbg[f];
  }
  const float4* qlg = (const float4*)(ql_g + (size_t)(b * NUM_Q + qt * 16) * D_ATT);
  const float4* qbg = (const float4*)(qb_g + (size_t)(b * NUM_Q + qt * 16) * D_ATT);
#pragma unroll
  for (int i = 0; i < 2; ++i) {
    const int idx = tid + i * 256;
    ((float4*)qlds)[idx] = qlg[idx];
    ((float4*)qblds)[idx] = qbg[idx];
  }
  if (tid < 32) {
    float4 t = ((const float4*)v_att)[tid];
    t.x *= -2.f; t.y *= -2.f; t.z *= -2.f; t.w *= -2.f;
    ((float4*)vlds)[tid] = t;
  }
  __syncthreads();

  const int k = tid & 63;
  const int w = tid >> 6;
  float accl[4] = {0.f, 0.f, 0.f, 0.f};
  float accb[4] = {0.f, 0.f, 0.f, 0.f};

  for (int d0 = 0; d0 < D_ATT; d0 += 8) {
    const int c = d0 >> 3;
    const int off = k * 256 + ((c ^ (k & 7)) << 4);
    const uint4 klv = *(const uint4*)(klds + off);
    const uint4 kbv = *(const uint4*)(kblds + off);
    float klf[8], kbf[8];
    unpack8(klv, klf);
    unpack8(kbv, kbf);
    float vv[8];
    *(float4*)&vv[0] = *(const float4*)&vlds[d0];
    *(float4*)&vv[4] = *(const float4*)&vlds[d0 + 4];
#pragma unroll
    for (int qq = 0; qq < 4; ++qq) {
      const int q = w * 4 + qq;
      float qlv[8], qbv2[8];
      *(float4*)&qlv[0] = *(const float4*)&qlds[q * D_ATT + d0];
      *(float4*)&qlv[4] = *(const float4*)&qlds[q * D_ATT + d0 + 4];
      *(float4*)&qbv2[0] = *(const float4*)&qblds[q * D_ATT + d0];
      *(float4*)&qbv2[4] = *(const float4*)&qblds[q * D_ATT + d0 + 4];
#pragma unroll
      for (int j = 0; j < 8; ++j) {
        const float s = qlv[j] + klf[j];
        const float e = fast_exp2(s);
        const float r = __builtin_amdgcn_rcpf(e + 1.0f);
        accl[qq] = fmaf(vv[j], r, accl[qq]);
        accb[qq] = fmaf(qbv2[j], kbf[j], accb[qq]);
      }
    }
  }

  const float cst = vsumc[0];
#pragma unroll
  for (int qq = 0; qq < 4; ++qq) {
    const int q = qt * 16 + w * 4 + qq;
    out[(size_t)(b * NUM_Q + q) * NUM_K + kt * 64 + k] = accl[qq] + accb[qq] + cst;
  }
}

extern "C" void kernel_launch(void* const* d_in, const int* in_sizes, int n_in,
                              void* d_out, int out_size, void* d_ws, size_t ws_size,
                              hipStream_t stream) {
  const float* query = (const float*)d_in[0];
  const float* key   = (const float*)d_in[1];
  const float* W_bq  = (const float*)d_in[2];
  const float* b_bq  = (const float*)d_in[3];
  const float* W_bk  = (const float*)d_in[4];
  const float* b_bk  = (const float*)d_in[5];
  const float* W_lq  = (const float*)d_in[6];
  const float* b_lq  = (const float*)d_in[7];
  const float* W_lk  = (const float*)d_in[8];
  const float* b_lk  = (const float*)d_in[9];
  const float* v_att = (const float*)d_in[10];
  const float* b_att = (const float*)d_in[11];

  // ws layout: ql(256KB) qb(256KB) kl(1MB) kb(1MB) Wt2(512KB) vsumc(4B) ~3.0MB
  float* ql = (float*)d_ws;
  float* qb = ql + 512 * D_ATT;
  uint16_t* kl = (uint16_t*)(qb + 512 * D_ATT);
  uint16_t* kb = kl + 4096 * D_ATT;
  uint16_t* Wt2 = kb + 4096 * D_ATT;
  float* vsumc = (float*)(Wt2 + 2 * 256 * 512);

  pack_w<<<128, 256, 0, stream>>>(W_lq, W_bq, W_lk, W_bk, v_att, b_att, Wt2, vsumc);
  proj_gemm<<<576, 256, 0, stream>>>(query, key, Wt2, b_lq, b_bq, b_lk, b_bk,
                                     ql, qb, kl, kb);
  fused_kernel<<<BSZ * 16 * 32, 256, 0, stream>>>(
      ql, qb, kl, kb, v_att, vsumc, (float*)d_out);
}

// Round 4
// 56.459 us; speedup vs baseline: 1.7916x; 1.2062x over previous
//
#include <hip/hip_runtime.h>
#include <hip/hip_bf16.h>
#include <cstdint>

#define DEV_INLINE __device__ __forceinline__

typedef __attribute__((ext_vector_type(8))) short short8v;   // 8 bf16 (4 VGPRs)
typedef __attribute__((ext_vector_type(4))) float f32x4;

constexpr int BSZ = 2, NUM_Q = 256, NUM_K = 2048, D_IN = 512, D_ATT = 128;
constexpr float S_ATT = 0.08838834764831845f;   // 1/sqrt(128)
constexpr float C2 = 2.8853900817779268f;       // 2*log2(e): exp2(C2*x) = e^{2x}

DEV_INLINE uint16_t f2bf(float f) {  // fp32 -> bf16 bits, round-nearest-even
  uint32_t u = __float_as_uint(f);
  return (uint16_t)((u + 0x7fffu + ((u >> 16) & 1u)) >> 16);
}

DEV_INLINE void unpack8(const uint4& u, float* f) {
  f[0] = __uint_as_float(u.x << 16); f[1] = __uint_as_float(u.x & 0xffff0000u);
  f[2] = __uint_as_float(u.y << 16); f[3] = __uint_as_float(u.y & 0xffff0000u);
  f[4] = __uint_as_float(u.z << 16); f[5] = __uint_as_float(u.z & 0xffff0000u);
  f[6] = __uint_as_float(u.w << 16); f[7] = __uint_as_float(u.w & 0xffff0000u);
}

DEV_INLINE float fast_exp2(float x) {
#if __has_builtin(__builtin_amdgcn_exp2f)
  return __builtin_amdgcn_exp2f(x);
#else
  return __expf(0.6931471805599453f * x);
#endif
}

// ---------------------------------------------------------------------------
// pack_w: fragment-packed Wt2. Chunk (mat, cb, s) = 64 lanes x 8 bf16 (1 KB):
//   lane l holds cols c = cb*16+(l&15), k = s*32+(l>>4)*8+j  (j=0..7)
//   addr(bf16) = ((mat*16+cb)*16+s)*512 + l*8
// Grid: 64 blocks = mat(2) x cb(16) x khalf(2); LDS transpose of a 256k x 16c
// slice. Also vsumc[0] = sum(v_att) + b_att (block 0).
// ---------------------------------------------------------------------------
__global__ __launch_bounds__(256) void pack_w(
    const float* __restrict__ Wlq, const float* __restrict__ Wbq,
    const float* __restrict__ Wlk, const float* __restrict__ Wbk,
    const float* __restrict__ v_att, const float* __restrict__ b_att,
    uint16_t* __restrict__ Wt2, float* __restrict__ vsumc) {
  __shared__ float xs[256 * 17];  // 17 KB, +1 pad
  const int bid = blockIdx.x;
  const int mat = bid >> 5, cb = (bid >> 1) & 15, kh = bid & 1;
  const int t = threadIdx.x;
  const float* W = (mat == 0) ? (cb < 8 ? Wlq : Wbq) : (cb < 8 ? Wlk : Wbk);
  const int cbase = (cb & 7) * 16;

  // stage: 256 k-rows x 16 cols, coalesced float4
#pragma unroll
  for (int i = 0; i < 4; ++i) {
    const int fq = t + i * 256;          // 1024 quads
    const int k = fq >> 2, c4 = (fq & 3) * 4;
    const float4 v = *(const float4*)&W[(size_t)(kh * 256 + k) * D_ATT + cbase + c4];
    xs[k * 17 + c4 + 0] = v.x;
    xs[k * 17 + c4 + 1] = v.y;
    xs[k * 17 + c4 + 2] = v.z;
    xs[k * 17 + c4 + 3] = v.w;
  }
  __syncthreads();

  // emit: 8 s-chunks x 64 lane-entries = 512 entries, 2 per thread
#pragma unroll
  for (int i = 0; i < 2; ++i) {
    const int e = t + i * 256;
    const int sl = e >> 6, l = e & 63;
    const int kb_ = sl * 32 + (l >> 4) * 8;
    const int c = l & 15;
    uint16_t o[8];
#pragma unroll
    for (int j = 0; j < 8; ++j) o[j] = f2bf(xs[(kb_ + j) * 17 + c]);
    const int sg = kh * 8 + sl;
    *(uint4*)(Wt2 + ((size_t)(mat * 16 + cb) * 16 + sg) * 512 + l * 8) =
        *(const uint4*)o;
  }

  if (bid == 0 && t < 64) {
    float s = v_att[t] + v_att[t + 64];
#pragma unroll
    for (int off = 32; off >= 1; off >>= 1) s += __shfl_down(s, off);
    if (t == 0) vsumc[0] = s + b_att[0];
  }
}

// ---------------------------------------------------------------------------
// proj_gemm: [query;key] (4608x512) @ Wt2 -> ql (fp32, xC2), qb (bf16, xS_ATT),
// kl (bf16, xC2), kb (bf16). One wave per 16 rows x 32 cols.
// Frag maps (validated by passing r3 bench):
//   A: row=lane&15, k=(lane>>4)*8+j;  B: col=lane&15, same k map.
//   C/D: col=lane&15, row=(lane>>4)*4+reg
// ---------------------------------------------------------------------------
__global__ __launch_bounds__(256) void proj_gemm(
    const float* __restrict__ Xq, const float* __restrict__ Xk,
    const uint16_t* __restrict__ Wt2,
    const float* __restrict__ b_lq, const float* __restrict__ b_bq,
    const float* __restrict__ b_lk, const float* __restrict__ b_bk,
    float* __restrict__ ql, uint16_t* __restrict__ qb,
    uint16_t* __restrict__ kl, uint16_t* __restrict__ kb) {
  const int wid = blockIdx.x * 4 + (threadIdx.x >> 6);  // 0..2303
  const int l = threadIdx.x & 63;
  const int rt = wid >> 3;   // 0..287 row-tile (16 rows)
  const int ct2 = wid & 7;   // 0..7  col-group (32 cols = 2 chunks)
  const bool isq = rt < 32;
  const float* X = isq ? Xq : Xk;
  const int mat = isq ? 0 : 1;
  const int row0 = isq ? rt * 16 : (rt - 32) * 16;
  const float* xrow = X + (size_t)(row0 + (l & 15)) * D_IN + (l >> 4) * 8;
  const uint16_t* wbase =
      Wt2 + ((size_t)(mat * 16 + ct2 * 2) * 16) * 512 + l * 8;

  f32x4 acc0 = {0.f, 0.f, 0.f, 0.f}, acc1 = {0.f, 0.f, 0.f, 0.f};
  for (int s = 0; s < 16; ++s) {
    const int k0 = s * 32;
    const float4 x0 = *(const float4*)(xrow + k0);
    const float4 x1 = *(const float4*)(xrow + k0 + 4);
    short8v a;
    a[0] = (short)f2bf(x0.x); a[1] = (short)f2bf(x0.y);
    a[2] = (short)f2bf(x0.z); a[3] = (short)f2bf(x0.w);
    a[4] = (short)f2bf(x1.x); a[5] = (short)f2bf(x1.y);
    a[6] = (short)f2bf(x1.z); a[7] = (short)f2bf(x1.w);
    const short8v b0 = *(const short8v*)(wbase + (size_t)s * 512);
    const short8v b1 = *(const short8v*)(wbase + (size_t)(16 + s) * 512);
    acc0 = __builtin_amdgcn_mfma_f32_16x16x32_bf16(a, b0, acc0, 0, 0, 0);
    acc1 = __builtin_amdgcn_mfma_f32_16x16x32_bf16(a, b1, acc1, 0, 0, 0);
  }

  const int lrow4 = (l >> 4) * 4;
#pragma unroll
  for (int half = 0; half < 2; ++half) {
    const f32x4 acc = half ? acc1 : acc0;
    const int cbb = ct2 * 32 + half * 16;  // wave-uniform col-block base
    const int cl = (cbb + (l & 15)) & 127;
    float bias;
    if (isq) bias = (cbb < 128) ? b_lq[cl] : b_bq[cl];
    else     bias = (cbb < 128) ? b_lk[cl] : b_bk[cl];
#pragma unroll
    for (int jr = 0; jr < 4; ++jr) {
      const int row = row0 + lrow4 + jr;
      const float val = acc[jr] + bias;
      if (isq) {
        if (cbb < 128) ql[row * D_ATT + cl] = val * C2;
        else           qb[row * D_ATT + cl] = f2bf(val * S_ATT);
      } else {
        if (cbb < 128) kl[row * D_ATT + cl] = f2bf(val * C2);
        else           kb[row * D_ATT + cl] = f2bf(val);
      }
    }
  }
}

// ---------------------------------------------------------------------------
// fused: out[b,q,k] = VSUM + b_att + sum_d (-2 v_d)*sigm + (qb.kb via MFMA)
//        sigm = 1/(1+exp2(ql+kl))   (ql,kl pre-scaled by 2*log2e)
// Block: 256 thr = 4 waves; tile 16 q x 64 k. LDS 29 KB -> 5 blocks/CU.
// Bilinear: wave w computes 16q x 16k (k0=w*16) with 4 MFMAs from global
// qb/kb (L2-hot), exchanged through sblds.
// ---------------------------------------------------------------------------
__global__ __launch_bounds__(256) void fused_kernel(
    const float* __restrict__ ql_g, const uint16_t* __restrict__ qb_g,
    const uint16_t* __restrict__ kl_g, const uint16_t* __restrict__ kb_g,
    const float* __restrict__ v_att, const float* __restrict__ vsumc,
    float* __restrict__ out) {
  __shared__ __align__(16) unsigned char klds[64 * 256];  // bf16, swizzled 16KB
  __shared__ float qlds[16 * D_ATT];                      // 8 KB
  __shared__ float vlds[D_ATT];                           // -2*v_att
  __shared__ float sblds[16 * 64];                        // bilinear C, 4 KB

  const int tid = threadIdx.x;
  const int b = blockIdx.x >> 9;
  const int qt = (blockIdx.x >> 5) & 15;
  const int kt = blockIdx.x & 31;

  // --- stage kl tile (64 rows x 256B, XOR-swizzled 16B chunks) ---
  const uint4* klg = (const uint4*)(kl_g + (size_t)(b * NUM_K + kt * 64) * D_ATT);
#pragma unroll
  for (int i = 0; i < 4; ++i) {
    const int f = tid + i * 256;
    const int kr = f >> 4, c = f & 15;
    *(uint4*)(klds + kr * 256 + ((c ^ (kr & 7)) << 4)) = klg[f];
  }
  // --- stage ql tile (16 x 128 fp32, linear) ---
  const float4* qlg = (const float4*)(ql_g + (size_t)(b * NUM_Q + qt * 16) * D_ATT);
#pragma unroll
  for (int i = 0; i < 2; ++i) {
    const int idx = tid + i * 256;
    ((float4*)qlds)[idx] = qlg[idx];
  }
  if (tid < 32) {
    float4 t = ((const float4*)v_att)[tid];
    t.x *= -2.f; t.y *= -2.f; t.z *= -2.f; t.w *= -2.f;
    ((float4*)vlds)[tid] = t;
  }

  // --- bilinear via MFMA: wave w -> k-range [w*16, w*16+16) ---
  {
    const int l = tid & 63;
    const int w = tid >> 6;
    const uint16_t* ap =
        qb_g + (size_t)(b * NUM_Q + qt * 16 + (l & 15)) * D_ATT + (l >> 4) * 8;
    const uint16_t* bp =
        kb_g + (size_t)(b * NUM_K + kt * 64 + w * 16 + (l & 15)) * D_ATT + (l >> 4) * 8;
    f32x4 acc = {0.f, 0.f, 0.f, 0.f};
#pragma unroll
    for (int s = 0; s < 4; ++s) {
      const short8v a = *(const short8v*)(ap + s * 32);
      const short8v bb = *(const short8v*)(bp + s * 32);
      acc = __builtin_amdgcn_mfma_f32_16x16x32_bf16(a, bb, acc, 0, 0, 0);
    }
    const int col = w * 16 + (l & 15);
    const int r0 = (l >> 4) * 4;
#pragma unroll
    for (int jr = 0; jr < 4; ++jr) sblds[(r0 + jr) * 64 + col] = acc[jr];
  }
  __syncthreads();

  // --- linear (tanh) path: thread = (k = tid&63, q-group w = tid>>6) ---
  const int k = tid & 63;
  const int w = tid >> 6;
  float accl[4] = {0.f, 0.f, 0.f, 0.f};

  for (int d0 = 0; d0 < D_ATT; d0 += 8) {
    const int c = d0 >> 3;
    const uint4 klv = *(const uint4*)(klds + k * 256 + ((c ^ (k & 7)) << 4));
    float klf[8];
    unpack8(klv, klf);
    float vv[8];
    *(float4*)&vv[0] = *(const float4*)&vlds[d0];
    *(float4*)&vv[4] = *(const float4*)&vlds[d0 + 4];
#pragma unroll
    for (int qq = 0; qq < 4; ++qq) {
      const int q = w * 4 + qq;
      float qlv[8];
      *(float4*)&qlv[0] = *(const float4*)&qlds[q * D_ATT + d0];
      *(float4*)&qlv[4] = *(const float4*)&qlds[q * D_ATT + d0 + 4];
#pragma unroll
      for (int j = 0; j < 8; ++j) {
        const float x = qlv[j] + klf[j];
        const float e = fast_exp2(x);
        const float r = __builtin_amdgcn_rcpf(e + 1.0f);
        accl[qq] = fmaf(vv[j], r, accl[qq]);
      }
    }
  }

  const float cst = vsumc[0];
#pragma unroll
  for (int qq = 0; qq < 4; ++qq) {
    const int q = qt * 16 + w * 4 + qq;
    out[(size_t)(b * NUM_Q + q) * NUM_K + kt * 64 + k] =
        accl[qq] + sblds[(w * 4 + qq) * 64 + k] + cst;
  }
}

extern "C" void kernel_launch(void* const* d_in, const int* in_sizes, int n_in,
                              void* d_out, int out_size, void* d_ws, size_t ws_size,
                              hipStream_t stream) {
  const float* query = (const float*)d_in[0];
  const float* key   = (const float*)d_in[1];
  const float* W_bq  = (const float*)d_in[2];
  const float* b_bq  = (const float*)d_in[3];
  const float* W_bk  = (const float*)d_in[4];
  const float* b_bk  = (const float*)d_in[5];
  const float* W_lq  = (const float*)d_in[6];
  const float* b_lq  = (const float*)d_in[7];
  const float* W_lk  = (const float*)d_in[8];
  const float* b_lk  = (const float*)d_in[9];
  const float* v_att = (const float*)d_in[10];
  const float* b_att = (const float*)d_in[11];

  // ws: ql f32 (256KB) | qb bf16 (128KB) | kl (1MB) | kb (1MB) | Wt2 (512KB) | vsumc
  float* ql = (float*)d_ws;
  uint16_t* qb = (uint16_t*)(ql + 512 * D_ATT);
  uint16_t* kl = qb + 512 * D_ATT;
  uint16_t* kb = kl + 4096 * D_ATT;
  uint16_t* Wt2 = kb + 4096 * D_ATT;
  float* vsumc = (float*)(Wt2 + 2 * 256 * 512);

  pack_w<<<64, 256, 0, stream>>>(W_lq, W_bq, W_lk, W_bk, v_att, b_att, Wt2, vsumc);
  proj_gemm<<<576, 256, 0, stream>>>(query, key, Wt2, b_lq, b_bq, b_lk, b_bk,
                                     ql, qb, kl, kb);
  fused_kernel<<<BSZ * 16 * 32, 256, 0, stream>>>(
      ql, qb, kl, kb, v_att, vsumc, (float*)d_out);
}

// Round 5
// 53.896 us; speedup vs baseline: 1.8768x; 1.0476x over previous
//
#include <hip/hip_runtime.h>
#include <hip/hip_bf16.h>
#include <cstdint>

#define DEV_INLINE __device__ __forceinline__

typedef __attribute__((ext_vector_type(8))) short short8v;   // 8 bf16 (4 VGPRs)
typedef __attribute__((ext_vector_type(4))) float f32x4;

constexpr int BSZ = 2, NUM_Q = 256, NUM_K = 2048, D_IN = 512, D_ATT = 128;
constexpr float S_ATT = 0.08838834764831845f;   // 1/sqrt(128)
constexpr float C2 = 2.8853900817779268f;       // 2*log2(e): exp2(C2*x) = e^{2x}

DEV_INLINE uint16_t f2bf(float f) {  // fp32 -> bf16 bits, round-nearest-even
  uint32_t u = __float_as_uint(f);
  return (uint16_t)((u + 0x7fffu + ((u >> 16) & 1u)) >> 16);
}

DEV_INLINE void unpack8(const uint4& u, float* f) {
  f[0] = __uint_as_float(u.x << 16); f[1] = __uint_as_float(u.x & 0xffff0000u);
  f[2] = __uint_as_float(u.y << 16); f[3] = __uint_as_float(u.y & 0xffff0000u);
  f[4] = __uint_as_float(u.z << 16); f[5] = __uint_as_float(u.z & 0xffff0000u);
  f[6] = __uint_as_float(u.w << 16); f[7] = __uint_as_float(u.w & 0xffff0000u);
}

DEV_INLINE float fast_exp2(float x) {
#if __has_builtin(__builtin_amdgcn_exp2f)
  return __builtin_amdgcn_exp2f(x);
#else
  return __expf(0.6931471805599453f * x);
#endif
}

// ---------------------------------------------------------------------------
// pack_w (blocks 0..63): fragment-packed Wt2, chunk (mat,cb,s) = 64 lanes x
// 8 bf16; lane l: cols cb*16+(l&15), k = s*32+(l>>4)*8+j. Block 0 also does
// vsumc[0] = sum(v_att)+b_att.
// blocks 64..1215: convert [query;key] fp32 -> Xbf bf16 (4608x512).
// ---------------------------------------------------------------------------
__global__ __launch_bounds__(256) void pack_w(
    const float* __restrict__ Wlq, const float* __restrict__ Wbq,
    const float* __restrict__ Wlk, const float* __restrict__ Wbk,
    const float* __restrict__ v_att, const float* __restrict__ b_att,
    const float* __restrict__ Xq, const float* __restrict__ Xk,
    uint16_t* __restrict__ Wt2, uint16_t* __restrict__ Xbf,
    float* __restrict__ vsumc) {
  __shared__ float xs[256 * 17];  // 17 KB, +1 pad
  const int bid = blockIdx.x;
  const int t = threadIdx.x;

  if (bid >= 64) {  // --- X conversion: 8 elems/thread ---
    const int flat = (bid - 64) * 2048 + t * 8;
    const float* src = (flat < 512 * D_IN) ? (Xq + flat) : (Xk + (flat - 512 * D_IN));
    const float4 a = *(const float4*)src;
    const float4 b = *(const float4*)(src + 4);
    uint16_t o[8];
    o[0] = f2bf(a.x); o[1] = f2bf(a.y); o[2] = f2bf(a.z); o[3] = f2bf(a.w);
    o[4] = f2bf(b.x); o[5] = f2bf(b.y); o[6] = f2bf(b.z); o[7] = f2bf(b.w);
    *(uint4*)(Xbf + flat) = *(const uint4*)o;
    return;
  }

  const int mat = bid >> 5, cb = (bid >> 1) & 15, kh = bid & 1;
  const float* W = (mat == 0) ? (cb < 8 ? Wlq : Wbq) : (cb < 8 ? Wlk : Wbk);
  const int cbase = (cb & 7) * 16;

#pragma unroll
  for (int i = 0; i < 4; ++i) {
    const int fq = t + i * 256;          // 1024 quads
    const int k = fq >> 2, c4 = (fq & 3) * 4;
    const float4 v = *(const float4*)&W[(size_t)(kh * 256 + k) * D_ATT + cbase + c4];
    xs[k * 17 + c4 + 0] = v.x;
    xs[k * 17 + c4 + 1] = v.y;
    xs[k * 17 + c4 + 2] = v.z;
    xs[k * 17 + c4 + 3] = v.w;
  }
  __syncthreads();

#pragma unroll
  for (int i = 0; i < 2; ++i) {
    const int e = t + i * 256;
    const int sl = e >> 6, l = e & 63;
    const int kb_ = sl * 32 + (l >> 4) * 8;
    const int c = l & 15;
    uint16_t o[8];
#pragma unroll
    for (int j = 0; j < 8; ++j) o[j] = f2bf(xs[(kb_ + j) * 17 + c]);
    const int sg = kh * 8 + sl;
    *(uint4*)(Wt2 + ((size_t)(mat * 16 + cb) * 16 + sg) * 512 + l * 8) =
        *(const uint4*)o;
  }

  if (bid == 0 && t < 64) {
    float s = v_att[t] + v_att[t + 64];
#pragma unroll
    for (int off = 32; off >= 1; off >>= 1) s += __shfl_down(s, off);
    if (t == 0) vsumc[0] = s + b_att[0];
  }
}

// ---------------------------------------------------------------------------
// proj_gemm: Xbf (4608x512 bf16) @ Wt2 -> ql (fp32, xC2), qb (bf16, xS_ATT),
// kl (bf16, xC2), kb (bf16). One wave per 16 rows x 32 cols.
// Frag maps (validated by r3/r4 passing):
//   A: row=lane&15, k=(lane>>4)*8+j;  B: col=lane&15, same k map.
//   C/D: col=lane&15, row=(lane>>4)*4+reg
// ---------------------------------------------------------------------------
__global__ __launch_bounds__(256) void proj_gemm(
    const uint16_t* __restrict__ Xbf, const uint16_t* __restrict__ Wt2,
    const float* __restrict__ b_lq, const float* __restrict__ b_bq,
    const float* __restrict__ b_lk, const float* __restrict__ b_bk,
    float* __restrict__ ql, uint16_t* __restrict__ qb,
    uint16_t* __restrict__ kl, uint16_t* __restrict__ kb) {
  const int wid = blockIdx.x * 4 + (threadIdx.x >> 6);  // 0..2303
  const int l = threadIdx.x & 63;
  const int rt = wid >> 3;   // 0..287 row-tile (16 rows)
  const int ct2 = wid & 7;   // 0..7  col-group (32 cols = 2 chunks)
  const bool isq = rt < 32;
  const int mat = isq ? 0 : 1;
  const int row0 = isq ? rt * 16 : (rt - 32) * 16;  // local row in q/k outputs
  const uint16_t* arow = Xbf + (size_t)(rt * 16 + (l & 15)) * D_IN + (l >> 4) * 8;
  const uint16_t* wbase =
      Wt2 + ((size_t)(mat * 16 + ct2 * 2) * 16) * 512 + l * 8;

  f32x4 acc0 = {0.f, 0.f, 0.f, 0.f}, acc1 = {0.f, 0.f, 0.f, 0.f};
#pragma unroll 4
  for (int s = 0; s < 16; ++s) {
    const short8v a = *(const short8v*)(arow + s * 32);
    const short8v b0 = *(const short8v*)(wbase + (size_t)s * 512);
    const short8v b1 = *(const short8v*)(wbase + (size_t)(16 + s) * 512);
    acc0 = __builtin_amdgcn_mfma_f32_16x16x32_bf16(a, b0, acc0, 0, 0, 0);
    acc1 = __builtin_amdgcn_mfma_f32_16x16x32_bf16(a, b1, acc1, 0, 0, 0);
  }

  const int lrow4 = (l >> 4) * 4;
#pragma unroll
  for (int half = 0; half < 2; ++half) {
    const f32x4 acc = half ? acc1 : acc0;
    const int cbb = ct2 * 32 + half * 16;  // wave-uniform col-block base
    const int cl = (cbb + (l & 15)) & 127;
    float bias;
    if (isq) bias = (cbb < 128) ? b_lq[cl] : b_bq[cl];
    else     bias = (cbb < 128) ? b_lk[cl] : b_bk[cl];
#pragma unroll
    for (int jr = 0; jr < 4; ++jr) {
      const int row = row0 + lrow4 + jr;
      const float val = acc[jr] + bias;
      if (isq) {
        if (cbb < 128) ql[row * D_ATT + cl] = val * C2;
        else           qb[row * D_ATT + cl] = f2bf(val * S_ATT);
      } else {
        if (cbb < 128) kl[row * D_ATT + cl] = f2bf(val * C2);
        else           kb[row * D_ATT + cl] = f2bf(val);
      }
    }
  }
}

// ---------------------------------------------------------------------------
// fused: out[b,q,k] = VSUM + b_att + sum_d (-2 v_d)*sigm + (qb.kb via MFMA)
//        sigm = 1/(1+exp2(ql+kl))   (ql,kl pre-scaled by 2*log2e)
// Block: 256 thr = 4 waves; tile 16 q x 64 k. LDS ~20.5 KB.
// ql read via wave-uniform (readfirstlane) global loads -> s_load/L1 bcast.
// Reciprocal batched 4-way: 1 v_rcp per 4 sigmoids (d>=1, no overflow).
// ---------------------------------------------------------------------------
__global__ __launch_bounds__(256) void fused_kernel(
    const float* __restrict__ ql_g, const uint16_t* __restrict__ qb_g,
    const uint16_t* __restrict__ kl_g, const uint16_t* __restrict__ kb_g,
    const float* __restrict__ v_att, const float* __restrict__ vsumc,
    float* __restrict__ out) {
  __shared__ __align__(16) unsigned char klds[64 * 256];  // bf16, swizzled 16KB
  __shared__ float vlds[D_ATT];                           // -2*v_att
  __shared__ float sblds[16 * 64];                        // bilinear C, 4 KB

  const int tid = threadIdx.x;
  const int b = blockIdx.x >> 9;
  const int qt = (blockIdx.x >> 5) & 15;
  const int kt = blockIdx.x & 31;

  // --- stage kl tile (64 rows x 256B, XOR-swizzled 16B chunks) ---
  const uint4* klg = (const uint4*)(kl_g + (size_t)(b * NUM_K + kt * 64) * D_ATT);
#pragma unroll
  for (int i = 0; i < 4; ++i) {
    const int f = tid + i * 256;
    const int kr = f >> 4, c = f & 15;
    *(uint4*)(klds + kr * 256 + ((c ^ (kr & 7)) << 4)) = klg[f];
  }
  if (tid < 32) {
    float4 t = ((const float4*)v_att)[tid];
    t.x *= -2.f; t.y *= -2.f; t.z *= -2.f; t.w *= -2.f;
    ((float4*)vlds)[tid] = t;
  }

  // --- bilinear via MFMA: wave w -> k-range [w*16, w*16+16) ---
  {
    const int l = tid & 63;
    const int w = tid >> 6;
    const uint16_t* ap =
        qb_g + (size_t)(b * NUM_Q + qt * 16 + (l & 15)) * D_ATT + (l >> 4) * 8;
    const uint16_t* bp =
        kb_g + (size_t)(b * NUM_K + kt * 64 + w * 16 + (l & 15)) * D_ATT + (l >> 4) * 8;
    f32x4 acc = {0.f, 0.f, 0.f, 0.f};
#pragma unroll
    for (int s = 0; s < 4; ++s) {
      const short8v a = *(const short8v*)(ap + s * 32);
      const short8v bb = *(const short8v*)(bp + s * 32);
      acc = __builtin_amdgcn_mfma_f32_16x16x32_bf16(a, bb, acc, 0, 0, 0);
    }
    const int col = w * 16 + (l & 15);
    const int r0 = (l >> 4) * 4;
#pragma unroll
    for (int jr = 0; jr < 4; ++jr) sblds[(r0 + jr) * 64 + col] = acc[jr];
  }
  __syncthreads();

  // --- linear (tanh->sigmoid) path: thread = (k = tid&63, q-group w) ---
  const int k = tid & 63;
  const int w = tid >> 6;
  // wave-uniform base for this wave's 4 q-rows (enables s_load scalarization)
  const int qoff =
      __builtin_amdgcn_readfirstlane((b * NUM_Q + qt * 16 + (tid >> 6) * 4) * D_ATT);
  const float* qbase = ql_g + qoff;

  float accl[4] = {0.f, 0.f, 0.f, 0.f};

  for (int d0 = 0; d0 < D_ATT; d0 += 8) {
    const int c = d0 >> 3;
    const uint4 klv = *(const uint4*)(klds + k * 256 + ((c ^ (k & 7)) << 4));
    float klf[8];
    unpack8(klv, klf);
    float vv[8];
    *(float4*)&vv[0] = *(const float4*)&vlds[d0];
    *(float4*)&vv[4] = *(const float4*)&vlds[d0 + 4];
#pragma unroll
    for (int qq = 0; qq < 4; ++qq) {
      float qv[8];
      *(float4*)&qv[0] = *(const float4*)(qbase + qq * D_ATT + d0);
      *(float4*)&qv[4] = *(const float4*)(qbase + qq * D_ATT + d0 + 4);
      float dd[8];
#pragma unroll
      for (int j = 0; j < 8; ++j) dd[j] = fast_exp2(qv[j] + klf[j]) + 1.0f;
#pragma unroll
      for (int g = 0; g < 8; g += 4) {
        const float p01 = dd[g] * dd[g + 1];
        const float p23 = dd[g + 2] * dd[g + 3];
        const float r = __builtin_amdgcn_rcpf(p01 * p23);
        const float r01 = r * p23, r23 = r * p01;
        accl[qq] = fmaf(vv[g],     r01 * dd[g + 1], accl[qq]);
        accl[qq] = fmaf(vv[g + 1], r01 * dd[g],     accl[qq]);
        accl[qq] = fmaf(vv[g + 2], r23 * dd[g + 3], accl[qq]);
        accl[qq] = fmaf(vv[g + 3], r23 * dd[g + 2], accl[qq]);
      }
    }
  }

  const float cst = vsumc[0];
#pragma unroll
  for (int qq = 0; qq < 4; ++qq) {
    const int q = qt * 16 + w * 4 + qq;
    out[(size_t)(b * NUM_Q + q) * NUM_K + kt * 64 + k] =
        accl[qq] + sblds[(w * 4 + qq) * 64 + k] + cst;
  }
}

extern "C" void kernel_launch(void* const* d_in, const int* in_sizes, int n_in,
                              void* d_out, int out_size, void* d_ws, size_t ws_size,
                              hipStream_t stream) {
  const float* query = (const float*)d_in[0];
  const float* key   = (const float*)d_in[1];
  const float* W_bq  = (const float*)d_in[2];
  const float* b_bq  = (const float*)d_in[3];
  const float* W_bk  = (const float*)d_in[4];
  const float* b_bk  = (const float*)d_in[5];
  const float* W_lq  = (const float*)d_in[6];
  const float* b_lq  = (const float*)d_in[7];
  const float* W_lk  = (const float*)d_in[8];
  const float* b_lk  = (const float*)d_in[9];
  const float* v_att = (const float*)d_in[10];
  const float* b_att = (const float*)d_in[11];

  // ws: ql f32 (256KB) | qb (128KB) | kl (1MB) | kb (1MB) | Wt2 (512KB)
  //   | Xbf (4.5MB) | vsumc
  float* ql = (float*)d_ws;
  uint16_t* qb = (uint16_t*)(ql + 512 * D_ATT);
  uint16_t* kl = qb + 512 * D_ATT;
  uint16_t* kb = kl + 4096 * D_ATT;
  uint16_t* Wt2 = kb + 4096 * D_ATT;
  uint16_t* Xbf = Wt2 + 2 * 256 * 512;
  float* vsumc = (float*)(Xbf + (size_t)4608 * 512);

  pack_w<<<64 + 1152, 256, 0, stream>>>(W_lq, W_bq, W_lk, W_bk, v_att, b_att,
                                        query, key, Wt2, Xbf, vsumc);
  proj_gemm<<<576, 256, 0, stream>>>(Xbf, Wt2, b_lq, b_bq, b_lk, b_bk,
                                     ql, qb, kl, kb);
  fused_kernel<<<BSZ * 16 * 32, 256, 0, stream>>>(
      ql, qb, kl, kb, v_att, vsumc, (float*)d_out);
}

// Round 6
// 40.103 us; speedup vs baseline: 2.5222x; 1.3439x over previous
//
#include <hip/hip_runtime.h>
#include <hip/hip_bf16.h>
#include <cstdint>

#define DEV_INLINE __device__ __forceinline__

typedef __attribute__((ext_vector_type(8))) short short8v;   // 8 bf16 (4 VGPRs)
typedef __attribute__((ext_vector_type(4))) float f32x4;

constexpr int BSZ = 2, NUM_Q = 256, NUM_K = 2048, D_IN = 512, D_ATT = 128;
constexpr float S_ATT = 0.08838834764831845f;   // 1/sqrt(128)
constexpr float C2 = 2.8853900817779268f;       // 2*log2(e): exp2(C2*x) = e^{2x}

DEV_INLINE uint16_t f2bf(float f) {  // fp32 -> bf16 bits, round-nearest-even
  uint32_t u = __float_as_uint(f);
  return (uint16_t)((u + 0x7fffu + ((u >> 16) & 1u)) >> 16);
}

DEV_INLINE void unpack8(const uint4& u, float* f) {
  f[0] = __uint_as_float(u.x << 16); f[1] = __uint_as_float(u.x & 0xffff0000u);
  f[2] = __uint_as_float(u.y << 16); f[3] = __uint_as_float(u.y & 0xffff0000u);
  f[4] = __uint_as_float(u.z << 16); f[5] = __uint_as_float(u.z & 0xffff0000u);
  f[6] = __uint_as_float(u.w << 16); f[7] = __uint_as_float(u.w & 0xffff0000u);
}

DEV_INLINE float fast_exp2(float x) {
#if __has_builtin(__builtin_amdgcn_exp2f)
  return __builtin_amdgcn_exp2f(x);
#else
  return __expf(0.6931471805599453f * x);
#endif
}

// ---------------------------------------------------------------------------
// pack_w (blocks 0..63): fragment-packed Wt2, chunk (mat,cb,s) = 64 lanes x
// 8 bf16; lane l: cols cb*16+(l&15), k = s*32+(l>>4)*8+j. Block 0 also does
// vsumc[0] = sum(v_att)+b_att.
// blocks 64..1215: convert [query;key] fp32 -> Xbf bf16 (4608x512).
// ---------------------------------------------------------------------------
__global__ __launch_bounds__(256) void pack_w(
    const float* __restrict__ Wlq, const float* __restrict__ Wbq,
    const float* __restrict__ Wlk, const float* __restrict__ Wbk,
    const float* __restrict__ v_att, const float* __restrict__ b_att,
    const float* __restrict__ Xq, const float* __restrict__ Xk,
    uint16_t* __restrict__ Wt2, uint16_t* __restrict__ Xbf,
    float* __restrict__ vsumc) {
  __shared__ float xs[256 * 17];  // 17 KB, +1 pad
  const int bid = blockIdx.x;
  const int t = threadIdx.x;

  if (bid >= 64) {  // --- X conversion: 8 elems/thread ---
    const int flat = (bid - 64) * 2048 + t * 8;
    const float* src = (flat < 512 * D_IN) ? (Xq + flat) : (Xk + (flat - 512 * D_IN));
    const float4 a = *(const float4*)src;
    const float4 b = *(const float4*)(src + 4);
    uint16_t o[8];
    o[0] = f2bf(a.x); o[1] = f2bf(a.y); o[2] = f2bf(a.z); o[3] = f2bf(a.w);
    o[4] = f2bf(b.x); o[5] = f2bf(b.y); o[6] = f2bf(b.z); o[7] = f2bf(b.w);
    *(uint4*)(Xbf + flat) = *(const uint4*)o;
    return;
  }

  const int mat = bid >> 5, cb = (bid >> 1) & 15, kh = bid & 1;
  const float* W = (mat == 0) ? (cb < 8 ? Wlq : Wbq) : (cb < 8 ? Wlk : Wbk);
  const int cbase = (cb & 7) * 16;

#pragma unroll
  for (int i = 0; i < 4; ++i) {
    const int fq = t + i * 256;          // 1024 quads
    const int k = fq >> 2, c4 = (fq & 3) * 4;
    const float4 v = *(const float4*)&W[(size_t)(kh * 256 + k) * D_ATT + cbase + c4];
    xs[k * 17 + c4 + 0] = v.x;
    xs[k * 17 + c4 + 1] = v.y;
    xs[k * 17 + c4 + 2] = v.z;
    xs[k * 17 + c4 + 3] = v.w;
  }
  __syncthreads();

#pragma unroll
  for (int i = 0; i < 2; ++i) {
    const int e = t + i * 256;
    const int sl = e >> 6, l = e & 63;
    const int kb_ = sl * 32 + (l >> 4) * 8;
    const int c = l & 15;
    uint16_t o[8];
#pragma unroll
    for (int j = 0; j < 8; ++j) o[j] = f2bf(xs[(kb_ + j) * 17 + c]);
    const int sg = kh * 8 + sl;
    *(uint4*)(Wt2 + ((size_t)(mat * 16 + cb) * 16 + sg) * 512 + l * 8) =
        *(const uint4*)o;
  }

  if (bid == 0 && t < 64) {
    float s = v_att[t] + v_att[t + 64];
#pragma unroll
    for (int off = 32; off >= 1; off >>= 1) s += __shfl_down(s, off);
    if (t == 0) vsumc[0] = s + b_att[0];
  }
}

// ---------------------------------------------------------------------------
// proj_gemm: Xbf (4608x512 bf16) @ Wt2. Epilogue now exponentiates the linear
// path: eq = exp2(C2*ql) fp32; ek = bf16(exp2(C2*kl)); qb bf16 (xS_ATT);
// kb bf16. Block = 4 waves sharing ONE 16-row A-tile staged in LDS
// (XOR-swizzled); rt = bid>>1, ct2 = (bid&1)*4 + wave.
// Frag maps (validated r3-r5): A row=lane&15, k=(lane>>4)*8+j; B col=lane&15;
// C/D col=lane&15, row=(lane>>4)*4+reg.
// ---------------------------------------------------------------------------
__global__ __launch_bounds__(256) void proj_gemm(
    const uint16_t* __restrict__ Xbf, const uint16_t* __restrict__ Wt2,
    const float* __restrict__ b_lq, const float* __restrict__ b_bq,
    const float* __restrict__ b_lk, const float* __restrict__ b_bk,
    float* __restrict__ eq, uint16_t* __restrict__ qb,
    uint16_t* __restrict__ ek, uint16_t* __restrict__ kb) {
  __shared__ __align__(16) unsigned char alds[16 * 1024];  // 16 rows x 512 bf16
  const int bid = blockIdx.x;           // 0..575
  const int t = threadIdx.x;
  const int l = t & 63;
  const int rt = bid >> 1;              // 0..287 (row-tile of 16)
  const int ct2 = (bid & 1) * 4 + (t >> 6);  // 0..7

  // stage A-tile: 1024 x 16B chunks; chunk f: row=f>>6, c=f&63 -> swizzled
  const uint4* ag = (const uint4*)(Xbf + (size_t)rt * 16 * D_IN);
#pragma unroll
  for (int i = 0; i < 4; ++i) {
    const int f = t + i * 256;
    const int row = f >> 6, c = f & 63;
    *(uint4*)(alds + row * 1024 + ((c ^ (row & 7)) << 4)) = ag[f];
  }
  __syncthreads();

  const bool isq = rt < 32;
  const int mat = isq ? 0 : 1;
  const int row0 = isq ? rt * 16 : (rt - 32) * 16;  // local row in q/k outputs
  const uint16_t* wbase =
      Wt2 + ((size_t)(mat * 16 + ct2 * 2) * 16) * 512 + l * 8;
  const int arow = l & 15;

  f32x4 acc0 = {0.f, 0.f, 0.f, 0.f}, acc1 = {0.f, 0.f, 0.f, 0.f};
#pragma unroll 4
  for (int s = 0; s < 16; ++s) {
    const int chunk = (s * 4 + (l >> 4)) ^ (arow & 7);
    const short8v a = *(const short8v*)(alds + arow * 1024 + (chunk << 4));
    const short8v b0 = *(const short8v*)(wbase + (size_t)s * 512);
    const short8v b1 = *(const short8v*)(wbase + (size_t)(16 + s) * 512);
    acc0 = __builtin_amdgcn_mfma_f32_16x16x32_bf16(a, b0, acc0, 0, 0, 0);
    acc1 = __builtin_amdgcn_mfma_f32_16x16x32_bf16(a, b1, acc1, 0, 0, 0);
  }

  const int lrow4 = (l >> 4) * 4;
#pragma unroll
  for (int half = 0; half < 2; ++half) {
    const f32x4 acc = half ? acc1 : acc0;
    const int cbb = ct2 * 32 + half * 16;  // wave-uniform col-block base
    const int cl = (cbb + (l & 15)) & 127;
    float bias;
    if (isq) bias = (cbb < 128) ? b_lq[cl] : b_bq[cl];
    else     bias = (cbb < 128) ? b_lk[cl] : b_bk[cl];
#pragma unroll
    for (int jr = 0; jr < 4; ++jr) {
      const int row = row0 + lrow4 + jr;
      const float val = acc[jr] + bias;
      if (isq) {
        if (cbb < 128) eq[row * D_ATT + cl] = fast_exp2(C2 * val);
        else           qb[row * D_ATT + cl] = f2bf(val * S_ATT);
      } else {
        if (cbb < 128) ek[row * D_ATT + cl] = f2bf(fast_exp2(C2 * val));
        else           kb[row * D_ATT + cl] = f2bf(val);
      }
    }
  }
}

// ---------------------------------------------------------------------------
// fused: out[b,q,k] = VSUM + b_att + sum_d (-2 v_d)/(1 + eq*ek) + (qb.kb MFMA)
//        eq = e^{2 ql} (fp32, wave-uniform s_loads), ek = e^{2 kl} (bf16, LDS)
// NO exp2 in the inner loop; 1 rcp per 4 elements (batched).
// Block: 256 thr = 4 waves; tile 16 q x 64 k. LDS ~20.5 KB.
// ---------------------------------------------------------------------------
__global__ __launch_bounds__(256) void fused_kernel(
    const float* __restrict__ eq_g, const uint16_t* __restrict__ qb_g,
    const uint16_t* __restrict__ ek_g, const uint16_t* __restrict__ kb_g,
    const float* __restrict__ v_att, const float* __restrict__ vsumc,
    float* __restrict__ out) {
  __shared__ __align__(16) unsigned char klds[64 * 256];  // ek bf16, swizzled
  __shared__ float vlds[D_ATT];                           // -2*v_att
  __shared__ float sblds[16 * 64];                        // bilinear C, 4 KB

  const int tid = threadIdx.x;
  const int b = blockIdx.x >> 9;
  const int qt = (blockIdx.x >> 5) & 15;
  const int kt = blockIdx.x & 31;

  // --- stage ek tile (64 rows x 256B, XOR-swizzled 16B chunks) ---
  const uint4* ekg = (const uint4*)(ek_g + (size_t)(b * NUM_K + kt * 64) * D_ATT);
#pragma unroll
  for (int i = 0; i < 4; ++i) {
    const int f = tid + i * 256;
    const int kr = f >> 4, c = f & 15;
    *(uint4*)(klds + kr * 256 + ((c ^ (kr & 7)) << 4)) = ekg[f];
  }
  if (tid < 32) {
    float4 t = ((const float4*)v_att)[tid];
    t.x *= -2.f; t.y *= -2.f; t.z *= -2.f; t.w *= -2.f;
    ((float4*)vlds)[tid] = t;
  }

  // --- bilinear via MFMA: wave w -> k-range [w*16, w*16+16) ---
  {
    const int l = tid & 63;
    const int w = tid >> 6;
    const uint16_t* ap =
        qb_g + (size_t)(b * NUM_Q + qt * 16 + (l & 15)) * D_ATT + (l >> 4) * 8;
    const uint16_t* bp =
        kb_g + (size_t)(b * NUM_K + kt * 64 + w * 16 + (l & 15)) * D_ATT + (l >> 4) * 8;
    f32x4 acc = {0.f, 0.f, 0.f, 0.f};
#pragma unroll
    for (int s = 0; s < 4; ++s) {
      const short8v a = *(const short8v*)(ap + s * 32);
      const short8v bb = *(const short8v*)(bp + s * 32);
      acc = __builtin_amdgcn_mfma_f32_16x16x32_bf16(a, bb, acc, 0, 0, 0);
    }
    const int col = w * 16 + (l & 15);
    const int r0 = (l >> 4) * 4;
#pragma unroll
    for (int jr = 0; jr < 4; ++jr) sblds[(r0 + jr) * 64 + col] = acc[jr];
  }
  __syncthreads();

  // --- linear path: thread = (k = tid&63, q-group w = tid>>6) ---
  const int k = tid & 63;
  const int w = tid >> 6;
  const int qoff =
      __builtin_amdgcn_readfirstlane((b * NUM_Q + qt * 16 + (tid >> 6) * 4) * D_ATT);
  const float* qbase = eq_g + qoff;

  float accl[4] = {0.f, 0.f, 0.f, 0.f};

  for (int d0 = 0; d0 < D_ATT; d0 += 8) {
    const int c = d0 >> 3;
    const uint4 ekv = *(const uint4*)(klds + k * 256 + ((c ^ (k & 7)) << 4));
    float ekf[8];
    unpack8(ekv, ekf);
    float vv[8];
    *(float4*)&vv[0] = *(const float4*)&vlds[d0];
    *(float4*)&vv[4] = *(const float4*)&vlds[d0 + 4];
#pragma unroll
    for (int qq = 0; qq < 4; ++qq) {
      float eqv[8];
      *(float4*)&eqv[0] = *(const float4*)(qbase + qq * D_ATT + d0);
      *(float4*)&eqv[4] = *(const float4*)(qbase + qq * D_ATT + d0 + 4);
      float dd[8];
#pragma unroll
      for (int j = 0; j < 8; ++j) dd[j] = fmaf(eqv[j], ekf[j], 1.0f);
#pragma unroll
      for (int g = 0; g < 8; g += 4) {
        const float p01 = dd[g] * dd[g + 1];
        const float p23 = dd[g + 2] * dd[g + 3];
        const float r = __builtin_amdgcn_rcpf(p01 * p23);
        const float r01 = r * p23, r23 = r * p01;
        accl[qq] = fmaf(vv[g],     r01 * dd[g + 1], accl[qq]);
        accl[qq] = fmaf(vv[g + 1], r01 * dd[g],     accl[qq]);
        accl[qq] = fmaf(vv[g + 2], r23 * dd[g + 3], accl[qq]);
        accl[qq] = fmaf(vv[g + 3], r23 * dd[g + 2], accl[qq]);
      }
    }
  }

  const float cst = vsumc[0];
#pragma unroll
  for (int qq = 0; qq < 4; ++qq) {
    const int q = qt * 16 + w * 4 + qq;
    out[(size_t)(b * NUM_Q + q) * NUM_K + kt * 64 + k] =
        accl[qq] + sblds[(w * 4 + qq) * 64 + k] + cst;
  }
}

extern "C" void kernel_launch(void* const* d_in, const int* in_sizes, int n_in,
                              void* d_out, int out_size, void* d_ws, size_t ws_size,
                              hipStream_t stream) {
  const float* query = (const float*)d_in[0];
  const float* key   = (const float*)d_in[1];
  const float* W_bq  = (const float*)d_in[2];
  const float* b_bq  = (const float*)d_in[3];
  const float* W_bk  = (const float*)d_in[4];
  const float* b_bk  = (const float*)d_in[5];
  const float* W_lq  = (const float*)d_in[6];
  const float* b_lq  = (const float*)d_in[7];
  const float* W_lk  = (const float*)d_in[8];
  const float* b_lk  = (const float*)d_in[9];
  const float* v_att = (const float*)d_in[10];
  const float* b_att = (const float*)d_in[11];

  // ws: eq f32 (256KB) | qb (128KB) | ek (1MB) | kb (1MB) | Wt2 (512KB)
  //   | Xbf (4.5MB) | vsumc
  float* eq = (float*)d_ws;
  uint16_t* qb = (uint16_t*)(eq + 512 * D_ATT);
  uint16_t* ek = qb + 512 * D_ATT;
  uint16_t* kb = ek + 4096 * D_ATT;
  uint16_t* Wt2 = kb + 4096 * D_ATT;
  uint16_t* Xbf = Wt2 + 2 * 256 * 512;
  float* vsumc = (float*)(Xbf + (size_t)4608 * 512);

  pack_w<<<64 + 1152, 256, 0, stream>>>(W_lq, W_bq, W_lk, W_bk, v_att, b_att,
                                        query, key, Wt2, Xbf, vsumc);
  proj_gemm<<<576, 256, 0, stream>>>(Xbf, Wt2, b_lq, b_bq, b_lk, b_bk,
                                     eq, qb, ek, kb);
  fused_kernel<<<BSZ * 16 * 32, 256, 0, stream>>>(
      eq, qb, ek, kb, v_att, vsumc, (float*)d_out);
}